// Round 5
// baseline (531.645 us; speedup 1.0000x reference)
//
#include <hip/hip_runtime.h>
#include <math.h>

#define N_PTS 4096
#define FB (N_PTS * 3)          // floats per batch = 12288
#define BLK 256
#define SPLIT 4                 // blocks per batch
#define STATS 17

__device__ inline float wave_reduce_sum_f32(float v) {
    #pragma unroll
    for (int off = 32; off > 0; off >>= 1) v += __shfl_xor(v, off, 64);
    return v;
}

// Fused: per-(batch, quarter) sufficient statistics in f32 -> ws, then the
// last block to finish (device-scope atomic counter) does all B eigensolves
// and writes the mean RMSD.
// ws layout: ws[bid*17 + {0..2}] = sum pred, {3..5} = sum true,
// {6} = sum ||pred||^2, {7} = sum ||true||^2, {8..16} = sum pred_i*true_j.
__global__ __launch_bounds__(BLK, 8) void kabsch_fused(const float* __restrict__ pred,
                                                       const float* __restrict__ tru,
                                                       float* __restrict__ ws,
                                                       unsigned int* __restrict__ cnt,
                                                       float* __restrict__ out,
                                                       int B, int nblocks) {
    const int bid = blockIdx.x;
    const int tid = threadIdx.x;
    const int b = bid >> 2, h = bid & 3;

    // Each block covers 1024 points = 768 float4s; each thread 3 consecutive
    // float4s (4 whole points), all 6 loads issued up front.
    const float4* P = reinterpret_cast<const float4*>(pred)
                      + (size_t)b * (FB / 4) + (size_t)h * (FB / 16) + (size_t)tid * 3;
    const float4* T = reinterpret_cast<const float4*>(tru)
                      + (size_t)b * (FB / 4) + (size_t)h * (FB / 16) + (size_t)tid * 3;
    float4 p0 = P[0], p1 = P[1], p2 = P[2];
    float4 t0 = T[0], t1 = T[1], t2 = T[2];

    float a[STATS];
    #pragma unroll
    for (int i = 0; i < STATS; ++i) a[i] = 0.0f;

#define ACC(px, py, pz, tx, ty, tz) do {                                        \
        a[0] += (px); a[1] += (py); a[2] += (pz);                               \
        a[3] += (tx); a[4] += (ty); a[5] += (tz);                               \
        a[6] = fmaf((px),(px), fmaf((py),(py), fmaf((pz),(pz), a[6])));         \
        a[7] = fmaf((tx),(tx), fmaf((ty),(ty), fmaf((tz),(tz), a[7])));         \
        a[8]  = fmaf((px),(tx), a[8]);  a[9]  = fmaf((px),(ty), a[9]);          \
        a[10] = fmaf((px),(tz), a[10]); a[11] = fmaf((py),(tx), a[11]);         \
        a[12] = fmaf((py),(ty), a[12]); a[13] = fmaf((py),(tz), a[13]);         \
        a[14] = fmaf((pz),(tx), a[14]); a[15] = fmaf((pz),(ty), a[15]);         \
        a[16] = fmaf((pz),(tz), a[16]);                                         \
    } while (0)

    ACC(p0.x, p0.y, p0.z, t0.x, t0.y, t0.z);
    ACC(p0.w, p1.x, p1.y, t0.w, t1.x, t1.y);
    ACC(p1.z, p1.w, p2.x, t1.z, t1.w, t2.x);
    ACC(p2.y, p2.z, p2.w, t2.y, t2.z, t2.w);
#undef ACC

    // Cheap tail: 2-stage butterfly -> every 4-lane group holds group sums,
    // transpose through LDS, 17 threads row-sum with float4 reads.
    #pragma unroll
    for (int i = 0; i < STATS; ++i) {
        a[i] += __shfl_xor(a[i], 1, 64);
        a[i] += __shfl_xor(a[i], 2, 64);
    }
    __shared__ float lds[STATS][BLK / 4 + 4];   // 17 x 68 (row stride 272B, 16B-aligned)
    const int grp = tid >> 2, sub = tid & 3;
    #pragma unroll
    for (int k = 0; k < 5; ++k) {
        const int s = sub + 4 * k;
        if (s < STATS) lds[s][grp] = a[s];
    }
    __syncthreads();
    if (tid < STATS) {
        const float4* row = reinterpret_cast<const float4*>(&lds[tid][0]);
        float4 acc4 = row[0];
        #pragma unroll
        for (int k = 1; k < BLK / 16; ++k) {
            float4 v = row[k];
            acc4.x += v.x; acc4.y += v.y; acc4.z += v.z; acc4.w += v.w;
        }
        ws[(size_t)bid * STATS + tid] = acc4.x + acc4.y + acc4.z + acc4.w;
    }

    // Last-block-done handshake (CUB decoupled pattern).
    __syncthreads();
    __threadfence();
    __shared__ unsigned int is_last;
    if (tid == 0) {
        unsigned int old = atomicAdd(cnt, 1u);
        is_last = (old == (unsigned int)(nblocks - 1)) ? 1u : 0u;
    }
    __syncthreads();
    if (!is_last) return;
    __threadfence();   // acquire side

    // Finalize: 256 threads, each handles B/256 batches.
    float local = 0.0f;
    for (int j = 0; j < (B + BLK - 1) / BLK; ++j) {
        const int bb = tid + j * BLK;
        if (bb >= B) break;
        float w[STATS];
        const float* base = ws + (size_t)bb * SPLIT * STATS;
        #pragma unroll
        for (int i = 0; i < STATS; ++i) {
            float s = 0.0f;
            #pragma unroll
            for (int hh = 0; hh < SPLIT; ++hh) s += base[hh * STATS + i];
            w[i] = s;
        }
        const float invN = 1.0f / (float)N_PTS;
        float sp[3] = {w[0], w[1], w[2]};
        float st[3] = {w[3], w[4], w[5]};
        float A[3][3];
        #pragma unroll
        for (int i = 0; i < 3; ++i)
            #pragma unroll
            for (int jj = 0; jj < 3; ++jj)
                A[i][jj] = w[8 + i * 3 + jj] - sp[i] * st[jj] * invN;
        float Sp = w[6] - (sp[0] * sp[0] + sp[1] * sp[1] + sp[2] * sp[2]) * invN;
        float St = w[7] - (st[0] * st[0] + st[1] * st[1] + st[2] * st[2]) * invN;

        float detA = A[0][0] * (A[1][1] * A[2][2] - A[1][2] * A[2][1])
                   - A[0][1] * (A[1][0] * A[2][2] - A[1][2] * A[2][0])
                   + A[0][2] * (A[1][0] * A[2][1] - A[1][1] * A[2][0]);

        float G00 = A[0][0]*A[0][0] + A[1][0]*A[1][0] + A[2][0]*A[2][0];
        float G11 = A[0][1]*A[0][1] + A[1][1]*A[1][1] + A[2][1]*A[2][1];
        float G22 = A[0][2]*A[0][2] + A[1][2]*A[1][2] + A[2][2]*A[2][2];
        float G01 = A[0][0]*A[0][1] + A[1][0]*A[1][1] + A[2][0]*A[2][1];
        float G02 = A[0][0]*A[0][2] + A[1][0]*A[1][2] + A[2][0]*A[2][2];
        float G12 = A[0][1]*A[0][2] + A[1][1]*A[1][2] + A[2][1]*A[2][2];

        float q = (G00 + G11 + G22) * (1.0f / 3.0f);
        float p1 = G01 * G01 + G02 * G02 + G12 * G12;
        float b00 = G00 - q, b11 = G11 - q, b22 = G22 - q;
        float p2 = b00 * b00 + b11 * b11 + b22 * b22 + 2.0f * p1;
        float p = sqrtf(p2 * (1.0f / 6.0f));
        float e1, e2, e3;
        if (p > 1e-30f + 1e-6f * fabsf(q)) {
            float ip = 1.0f / p;
            float C00 = b00 * ip, C11 = b11 * ip, C22 = b22 * ip;
            float C01 = G01 * ip, C02 = G02 * ip, C12 = G12 * ip;
            float r = 0.5f * (C00 * (C11 * C22 - C12 * C12)
                            - C01 * (C01 * C22 - C12 * C02)
                            + C02 * (C01 * C12 - C11 * C02));
            r = fminf(1.0f, fmaxf(-1.0f, r));
            float phi = acosf(r) * (1.0f / 3.0f);
            e1 = q + 2.0f * p * __cosf(phi);
            e3 = q + 2.0f * p * __cosf(phi + 2.0943951023931953f);  // + 2*pi/3
            e2 = 3.0f * q - e1 - e3;
        } else {
            e1 = e2 = e3 = q;
        }
        float s1 = sqrtf(fmaxf(e1, 0.0f));
        float s2 = sqrtf(fmaxf(e2, 0.0f));
        float s3 = sqrtf(fmaxf(e3, 0.0f));
        float d = (detA < 0.0f) ? -1.0f : 1.0f;
        float tr = s1 + s2 + d * s3;
        float msd = (Sp + St - 2.0f * tr) * invN;
        local += sqrtf(fmaxf(msd, 0.0f));
    }

    local = wave_reduce_sum_f32(local);
    __shared__ float red[4];
    if ((tid & 63) == 0) red[tid >> 6] = local;
    __syncthreads();
    if (tid == 0) out[0] = (red[0] + red[1] + red[2] + red[3]) / (float)B;
}

extern "C" void kernel_launch(void* const* d_in, const int* in_sizes, int n_in,
                              void* d_out, int out_size, void* d_ws, size_t ws_size,
                              hipStream_t stream) {
    const float* pred = (const float*)d_in[0];
    const float* tru  = (const float*)d_in[1];
    float* out = (float*)d_out;
    const int B = in_sizes[0] / FB;            // 1024
    const int nblocks = B * SPLIT;             // 4096

    float* ws = (float*)d_ws;                                    // stats region
    unsigned int* cnt = (unsigned int*)((char*)d_ws + (size_t)nblocks * STATS * sizeof(float));

    hipMemsetAsync(cnt, 0, sizeof(unsigned int), stream);        // reset handshake each call
    kabsch_fused<<<dim3(nblocks), dim3(BLK), 0, stream>>>(pred, tru, ws, cnt, out, B, nblocks);
}

// Round 6
// 403.554 us; speedup vs baseline: 1.3174x; 1.3174x over previous
//
#include <hip/hip_runtime.h>
#include <math.h>

#define N_PTS 4096
#define FB (N_PTS * 3)          // floats per batch = 12288
#define BLK 256
#define SPLIT 4                 // blocks per batch
#define STATS 17

__device__ inline float wave_reduce_sum_f32(float v) {
    #pragma unroll
    for (int off = 32; off > 0; off >>= 1) v += __shfl_xor(v, off, 64);
    return v;
}

// Fused: per-(batch, quarter) sufficient statistics in f32 -> ws, then the
// last block to finish (device-scope atomic counter) does all B eigensolves
// and writes the mean RMSD.
// ws layout: ws[bid*17 + {0..2}] = sum pred, {3..5} = sum true,
// {6} = sum ||pred||^2, {7} = sum ||true||^2, {8..16} = sum pred_i*true_j.
// NOTE: launch_bounds min-waves/EU kept at 4 (128-VGPR budget). Asking for 8
// (r5) capped VGPRs at 64 -> full spill to scratch, 70 MB scratch writes,
// 636 us. The ~60 live values here need the 128-VGPR budget.
__global__ __launch_bounds__(BLK, 4) void kabsch_fused(const float* __restrict__ pred,
                                                       const float* __restrict__ tru,
                                                       float* __restrict__ ws,
                                                       unsigned int* __restrict__ cnt,
                                                       float* __restrict__ out,
                                                       int B, int nblocks) {
    const int bid = blockIdx.x;
    const int tid = threadIdx.x;
    const int b = bid >> 2, h = bid & 3;

    // Each block covers 1024 points = 768 float4s; each thread 3 consecutive
    // float4s (4 whole points), all 6 loads issued up front.
    const float4* P = reinterpret_cast<const float4*>(pred)
                      + (size_t)b * (FB / 4) + (size_t)h * (FB / 16) + (size_t)tid * 3;
    const float4* T = reinterpret_cast<const float4*>(tru)
                      + (size_t)b * (FB / 4) + (size_t)h * (FB / 16) + (size_t)tid * 3;
    float4 p0 = P[0], p1 = P[1], p2 = P[2];
    float4 t0 = T[0], t1 = T[1], t2 = T[2];

    float a[STATS];
    #pragma unroll
    for (int i = 0; i < STATS; ++i) a[i] = 0.0f;

#define ACC(px, py, pz, tx, ty, tz) do {                                        \
        a[0] += (px); a[1] += (py); a[2] += (pz);                               \
        a[3] += (tx); a[4] += (ty); a[5] += (tz);                               \
        a[6] = fmaf((px),(px), fmaf((py),(py), fmaf((pz),(pz), a[6])));         \
        a[7] = fmaf((tx),(tx), fmaf((ty),(ty), fmaf((tz),(tz), a[7])));         \
        a[8]  = fmaf((px),(tx), a[8]);  a[9]  = fmaf((px),(ty), a[9]);          \
        a[10] = fmaf((px),(tz), a[10]); a[11] = fmaf((py),(tx), a[11]);         \
        a[12] = fmaf((py),(ty), a[12]); a[13] = fmaf((py),(tz), a[13]);         \
        a[14] = fmaf((pz),(tx), a[14]); a[15] = fmaf((pz),(ty), a[15]);         \
        a[16] = fmaf((pz),(tz), a[16]);                                         \
    } while (0)

    ACC(p0.x, p0.y, p0.z, t0.x, t0.y, t0.z);
    ACC(p0.w, p1.x, p1.y, t0.w, t1.x, t1.y);
    ACC(p1.z, p1.w, p2.x, t1.z, t1.w, t2.x);
    ACC(p2.y, p2.z, p2.w, t2.y, t2.z, t2.w);
#undef ACC

    // Cheap tail: 2-stage butterfly -> every 4-lane group holds group sums,
    // transpose through LDS, 17 threads row-sum with float4 reads.
    #pragma unroll
    for (int i = 0; i < STATS; ++i) {
        a[i] += __shfl_xor(a[i], 1, 64);
        a[i] += __shfl_xor(a[i], 2, 64);
    }
    __shared__ float lds[STATS][BLK / 4 + 4];   // 17 x 68 (row stride 272B, 16B-aligned)
    const int grp = tid >> 2, sub = tid & 3;
    #pragma unroll
    for (int k = 0; k < 5; ++k) {
        const int s = sub + 4 * k;
        if (s < STATS) lds[s][grp] = a[s];
    }
    __syncthreads();
    if (tid < STATS) {
        const float4* row = reinterpret_cast<const float4*>(&lds[tid][0]);
        float4 acc4 = row[0];
        #pragma unroll
        for (int k = 1; k < BLK / 16; ++k) {
            float4 v = row[k];
            acc4.x += v.x; acc4.y += v.y; acc4.z += v.z; acc4.w += v.w;
        }
        ws[(size_t)bid * STATS + tid] = acc4.x + acc4.y + acc4.z + acc4.w;
    }

    // Last-block-done handshake (CUB decoupled pattern).
    __syncthreads();
    __threadfence();
    __shared__ unsigned int is_last;
    if (tid == 0) {
        unsigned int old = atomicAdd(cnt, 1u);
        is_last = (old == (unsigned int)(nblocks - 1)) ? 1u : 0u;
    }
    __syncthreads();
    if (!is_last) return;
    __threadfence();   // acquire side

    // Finalize: 256 threads, each handles B/256 batches.
    float local = 0.0f;
    for (int j = 0; j < (B + BLK - 1) / BLK; ++j) {
        const int bb = tid + j * BLK;
        if (bb >= B) break;
        float w[STATS];
        const float* base = ws + (size_t)bb * SPLIT * STATS;
        #pragma unroll
        for (int i = 0; i < STATS; ++i) {
            float s = 0.0f;
            #pragma unroll
            for (int hh = 0; hh < SPLIT; ++hh) s += base[hh * STATS + i];
            w[i] = s;
        }
        const float invN = 1.0f / (float)N_PTS;
        float sp[3] = {w[0], w[1], w[2]};
        float st[3] = {w[3], w[4], w[5]};
        float A[3][3];
        #pragma unroll
        for (int i = 0; i < 3; ++i)
            #pragma unroll
            for (int jj = 0; jj < 3; ++jj)
                A[i][jj] = w[8 + i * 3 + jj] - sp[i] * st[jj] * invN;
        float Sp = w[6] - (sp[0] * sp[0] + sp[1] * sp[1] + sp[2] * sp[2]) * invN;
        float St = w[7] - (st[0] * st[0] + st[1] * st[1] + st[2] * st[2]) * invN;

        float detA = A[0][0] * (A[1][1] * A[2][2] - A[1][2] * A[2][1])
                   - A[0][1] * (A[1][0] * A[2][2] - A[1][2] * A[2][0])
                   + A[0][2] * (A[1][0] * A[2][1] - A[1][1] * A[2][0]);

        float G00 = A[0][0]*A[0][0] + A[1][0]*A[1][0] + A[2][0]*A[2][0];
        float G11 = A[0][1]*A[0][1] + A[1][1]*A[1][1] + A[2][1]*A[2][1];
        float G22 = A[0][2]*A[0][2] + A[1][2]*A[1][2] + A[2][2]*A[2][2];
        float G01 = A[0][0]*A[0][1] + A[1][0]*A[1][1] + A[2][0]*A[2][1];
        float G02 = A[0][0]*A[0][2] + A[1][0]*A[1][2] + A[2][0]*A[2][2];
        float G12 = A[0][1]*A[0][2] + A[1][1]*A[1][2] + A[2][1]*A[2][2];

        float q = (G00 + G11 + G22) * (1.0f / 3.0f);
        float p1 = G01 * G01 + G02 * G02 + G12 * G12;
        float b00 = G00 - q, b11 = G11 - q, b22 = G22 - q;
        float p2 = b00 * b00 + b11 * b11 + b22 * b22 + 2.0f * p1;
        float p = sqrtf(p2 * (1.0f / 6.0f));
        float e1, e2, e3;
        if (p > 1e-30f + 1e-6f * fabsf(q)) {
            float ip = 1.0f / p;
            float C00 = b00 * ip, C11 = b11 * ip, C22 = b22 * ip;
            float C01 = G01 * ip, C02 = G02 * ip, C12 = G12 * ip;
            float r = 0.5f * (C00 * (C11 * C22 - C12 * C12)
                            - C01 * (C01 * C22 - C12 * C02)
                            + C02 * (C01 * C12 - C11 * C02));
            r = fminf(1.0f, fmaxf(-1.0f, r));
            float phi = acosf(r) * (1.0f / 3.0f);
            e1 = q + 2.0f * p * __cosf(phi);
            e3 = q + 2.0f * p * __cosf(phi + 2.0943951023931953f);  // + 2*pi/3
            e2 = 3.0f * q - e1 - e3;
        } else {
            e1 = e2 = e3 = q;
        }
        float s1 = sqrtf(fmaxf(e1, 0.0f));
        float s2 = sqrtf(fmaxf(e2, 0.0f));
        float s3 = sqrtf(fmaxf(e3, 0.0f));
        float d = (detA < 0.0f) ? -1.0f : 1.0f;
        float tr = s1 + s2 + d * s3;
        float msd = (Sp + St - 2.0f * tr) * invN;
        local += sqrtf(fmaxf(msd, 0.0f));
    }

    local = wave_reduce_sum_f32(local);
    __shared__ float red[4];
    if ((tid & 63) == 0) red[tid >> 6] = local;
    __syncthreads();
    if (tid == 0) out[0] = (red[0] + red[1] + red[2] + red[3]) / (float)B;
}

extern "C" void kernel_launch(void* const* d_in, const int* in_sizes, int n_in,
                              void* d_out, int out_size, void* d_ws, size_t ws_size,
                              hipStream_t stream) {
    const float* pred = (const float*)d_in[0];
    const float* tru  = (const float*)d_in[1];
    float* out = (float*)d_out;
    const int B = in_sizes[0] / FB;            // 1024
    const int nblocks = B * SPLIT;             // 4096

    float* ws = (float*)d_ws;                                    // stats region
    unsigned int* cnt = (unsigned int*)((char*)d_ws + (size_t)nblocks * STATS * sizeof(float));

    hipMemsetAsync(cnt, 0, sizeof(unsigned int), stream);        // reset handshake each call
    kabsch_fused<<<dim3(nblocks), dim3(BLK), 0, stream>>>(pred, tru, ws, cnt, out, B, nblocks);
}

// Round 7
// 32.183 us; speedup vs baseline: 16.5195x; 12.5394x over previous
//
#include <hip/hip_runtime.h>
#include <math.h>

#define N_PTS 4096
#define FB (N_PTS * 3)          // floats per batch = 12288
#define BLK 256
#define SPLIT 4                 // blocks per batch
#define STATS 17

__device__ inline float wave_reduce_sum_f32(float v) {
    #pragma unroll
    for (int off = 32; off > 0; off >>= 1) v += __shfl_xor(v, off, 64);
    return v;
}

// Kernel 1: per-(batch, quarter) sufficient statistics in f32.
// ws[bid*17 + {0..2}] = sum pred, {3..5} = sum true, {6} = sum ||pred||^2,
// {7} = sum ||true||^2, {8..16} = sum pred_i * true_j (row-major 3x3).
// Design: 4 points/thread -> 6 dwordx4 preloaded + 17 f32 accumulators
// (~50 live VGPRs) so the allocator can reach 8 waves/SIMD. NO cross-block
// communication: a per-block __threadfence on CDNA4 = whole-XCD-L2 writeback
// (r5/r6: 4096 fences -> 420 us of idle waves). Two kernels are cheaper.
__global__ __launch_bounds__(BLK) void kabsch_reduce(const float* __restrict__ pred,
                                                     const float* __restrict__ tru,
                                                     float* __restrict__ ws) {
    const int bid = blockIdx.x;
    const int tid = threadIdx.x;
    const int b = bid >> 2, h = bid & 3;

    // Block covers 1024 points = 768 float4s; thread: 3 consecutive float4s
    // (4 whole points) per array, all 6 loads issued up front.
    const float4* P = reinterpret_cast<const float4*>(pred)
                      + (size_t)b * (FB / 4) + (size_t)h * (FB / 16) + (size_t)tid * 3;
    const float4* T = reinterpret_cast<const float4*>(tru)
                      + (size_t)b * (FB / 4) + (size_t)h * (FB / 16) + (size_t)tid * 3;
    float4 p0 = P[0], p1 = P[1], p2 = P[2];
    float4 t0 = T[0], t1 = T[1], t2 = T[2];

    float a[STATS];
    #pragma unroll
    for (int i = 0; i < STATS; ++i) a[i] = 0.0f;

#define ACC(px, py, pz, tx, ty, tz) do {                                        \
        a[0] += (px); a[1] += (py); a[2] += (pz);                               \
        a[3] += (tx); a[4] += (ty); a[5] += (tz);                               \
        a[6] = fmaf((px),(px), fmaf((py),(py), fmaf((pz),(pz), a[6])));         \
        a[7] = fmaf((tx),(tx), fmaf((ty),(ty), fmaf((tz),(tz), a[7])));         \
        a[8]  = fmaf((px),(tx), a[8]);  a[9]  = fmaf((px),(ty), a[9]);          \
        a[10] = fmaf((px),(tz), a[10]); a[11] = fmaf((py),(tx), a[11]);         \
        a[12] = fmaf((py),(ty), a[12]); a[13] = fmaf((py),(tz), a[13]);         \
        a[14] = fmaf((pz),(tx), a[14]); a[15] = fmaf((pz),(ty), a[15]);         \
        a[16] = fmaf((pz),(tz), a[16]);                                         \
    } while (0)

    ACC(p0.x, p0.y, p0.z, t0.x, t0.y, t0.z);
    ACC(p0.w, p1.x, p1.y, t0.w, t1.x, t1.y);
    ACC(p1.z, p1.w, p2.x, t1.z, t1.w, t2.x);
    ACC(p2.y, p2.z, p2.w, t2.y, t2.z, t2.w);
#undef ACC

    // Cheap tail: 2-stage butterfly -> every 4-lane group holds group sums,
    // transpose through LDS, 17 threads row-sum with float4 reads.
    #pragma unroll
    for (int i = 0; i < STATS; ++i) {
        a[i] += __shfl_xor(a[i], 1, 64);
        a[i] += __shfl_xor(a[i], 2, 64);
    }
    __shared__ float lds[STATS][BLK / 4 + 4];   // 17 x 68 (row stride 272B, 16B-aligned)
    const int grp = tid >> 2, sub = tid & 3;
    #pragma unroll
    for (int k = 0; k < 5; ++k) {
        const int s = sub + 4 * k;
        if (s < STATS) lds[s][grp] = a[s];
    }
    __syncthreads();
    if (tid < STATS) {
        const float4* row = reinterpret_cast<const float4*>(&lds[tid][0]);
        float4 acc4 = row[0];
        #pragma unroll
        for (int k = 1; k < BLK / 16; ++k) {
            float4 v = row[k];
            acc4.x += v.x; acc4.y += v.y; acc4.z += v.z; acc4.w += v.w;
        }
        ws[(size_t)bid * STATS + tid] = acc4.x + acc4.y + acc4.z + acc4.w;
    }
}

// Kernel 2: per-batch 3x3 closed-form singular values + RMSD, all f32, mean over B.
__global__ __launch_bounds__(1024) void kabsch_finalize(const float* __restrict__ ws,
                                                        float* __restrict__ out, int B) {
    const int tid = threadIdx.x;
    float rmsd = 0.0f;
    if (tid < B) {
        float w[STATS];
        const float* base = ws + (size_t)tid * SPLIT * STATS;
        #pragma unroll
        for (int i = 0; i < STATS; ++i) {
            float s = 0.0f;
            #pragma unroll
            for (int hh = 0; hh < SPLIT; ++hh) s += base[hh * STATS + i];
            w[i] = s;
        }
        const float invN = 1.0f / (float)N_PTS;
        float sp[3] = {w[0], w[1], w[2]};
        float st[3] = {w[3], w[4], w[5]};
        float A[3][3];
        #pragma unroll
        for (int i = 0; i < 3; ++i)
            #pragma unroll
            for (int j = 0; j < 3; ++j)
                A[i][j] = w[8 + i * 3 + j] - sp[i] * st[j] * invN;
        float Sp = w[6] - (sp[0] * sp[0] + sp[1] * sp[1] + sp[2] * sp[2]) * invN;
        float St = w[7] - (st[0] * st[0] + st[1] * st[1] + st[2] * st[2]) * invN;

        float detA = A[0][0] * (A[1][1] * A[2][2] - A[1][2] * A[2][1])
                   - A[0][1] * (A[1][0] * A[2][2] - A[1][2] * A[2][0])
                   + A[0][2] * (A[1][0] * A[2][1] - A[1][1] * A[2][0]);

        // G = A^T A (symmetric, PSD)
        float G00 = A[0][0]*A[0][0] + A[1][0]*A[1][0] + A[2][0]*A[2][0];
        float G11 = A[0][1]*A[0][1] + A[1][1]*A[1][1] + A[2][1]*A[2][1];
        float G22 = A[0][2]*A[0][2] + A[1][2]*A[1][2] + A[2][2]*A[2][2];
        float G01 = A[0][0]*A[0][1] + A[1][0]*A[1][1] + A[2][0]*A[2][1];
        float G02 = A[0][0]*A[0][2] + A[1][0]*A[1][2] + A[2][0]*A[2][2];
        float G12 = A[0][1]*A[0][2] + A[1][1]*A[1][2] + A[2][1]*A[2][2];

        // Closed-form symmetric 3x3 eigenvalues (descending e1 >= e2 >= e3).
        float q = (G00 + G11 + G22) * (1.0f / 3.0f);
        float p1 = G01 * G01 + G02 * G02 + G12 * G12;
        float b00 = G00 - q, b11 = G11 - q, b22 = G22 - q;
        float p2 = b00 * b00 + b11 * b11 + b22 * b22 + 2.0f * p1;
        float p = sqrtf(p2 * (1.0f / 6.0f));
        float e1, e2, e3;
        if (p > 1e-30f + 1e-6f * fabsf(q)) {
            float ip = 1.0f / p;
            float C00 = b00 * ip, C11 = b11 * ip, C22 = b22 * ip;
            float C01 = G01 * ip, C02 = G02 * ip, C12 = G12 * ip;
            float r = 0.5f * (C00 * (C11 * C22 - C12 * C12)
                            - C01 * (C01 * C22 - C12 * C02)
                            + C02 * (C01 * C12 - C11 * C02));
            r = fminf(1.0f, fmaxf(-1.0f, r));
            float phi = acosf(r) * (1.0f / 3.0f);
            e1 = q + 2.0f * p * __cosf(phi);
            e3 = q + 2.0f * p * __cosf(phi + 2.0943951023931953f);  // + 2*pi/3
            e2 = 3.0f * q - e1 - e3;
        } else {
            e1 = e2 = e3 = q;
        }
        float s1 = sqrtf(fmaxf(e1, 0.0f));
        float s2 = sqrtf(fmaxf(e2, 0.0f));
        float s3 = sqrtf(fmaxf(e3, 0.0f));  // smallest singular value
        float d = (detA < 0.0f) ? -1.0f : 1.0f;
        float tr = s1 + s2 + d * s3;
        float msd = (Sp + St - 2.0f * tr) * invN;
        rmsd = sqrtf(fmaxf(msd, 0.0f));
    }

    rmsd = wave_reduce_sum_f32(rmsd);
    __shared__ float red[16];
    const int lane = tid & 63, wid = tid >> 6;
    if (lane == 0) red[wid] = rmsd;
    __syncthreads();
    if (tid == 0) {
        float tot = 0.0f;
        #pragma unroll
        for (int w = 0; w < 16; ++w) tot += red[w];
        out[0] = tot / (float)B;
    }
}

extern "C" void kernel_launch(void* const* d_in, const int* in_sizes, int n_in,
                              void* d_out, int out_size, void* d_ws, size_t ws_size,
                              hipStream_t stream) {
    const float* pred = (const float*)d_in[0];
    const float* tru  = (const float*)d_in[1];
    float* out = (float*)d_out;
    float* ws = (float*)d_ws;
    const int B = in_sizes[0] / FB;            // 1024
    const int nblocks = B * SPLIT;             // 4096

    kabsch_reduce<<<dim3(nblocks), dim3(BLK), 0, stream>>>(pred, tru, ws);
    kabsch_finalize<<<dim3(1), dim3(1024), 0, stream>>>(ws, out, B);
}

// Round 8
// 27.456 us; speedup vs baseline: 19.3635x; 1.1722x over previous
//
#include <hip/hip_runtime.h>
#include <math.h>

#define N_PTS 4096
#define FB (N_PTS * 3)          // floats per batch = 12288
#define BLK 256
#define SPLIT 4                 // blocks per batch
#define PPB (N_PTS / SPLIT)     // 1024 points per block
#define F4PB (PPB * 3 / 4)      // 768 float4s per array per block
#define STATS 17

__device__ inline float wave_reduce_sum_f32(float v) {
    #pragma unroll
    for (int off = 32; off > 0; off >>= 1) v += __shfl_xor(v, off, 64);
    return v;
}

// Kernel 1: per-(batch, quarter) sufficient statistics in f32.
// ws layout is STAT-MAJOR: ws[s*nblocks + bid], so the finalize kernel reads
// each batch's 4 split-partials as one coalesced float4.
// Load path: every global_load_dwordx4 is lane-stride-16B coalesced
// (f = g*BLK+tid over the float4 space) -> 16 cache lines/instr. The previous
// rounds' "3 consecutive float4s per thread" pattern had 48B lane stride ->
// ~48 lines/instr, 3x the L1/L2 transactions on every tier (the structure-
// invariant ~3.5 TB/s wall seen in r1-r7). Point-aligned math is recovered by
// staging through a linear 24KB LDS tile and re-reading per-thread points.
__global__ __launch_bounds__(BLK) void kabsch_reduce(const float4* __restrict__ pred4,
                                                     const float4* __restrict__ tru4,
                                                     float* __restrict__ ws, int nblocks) {
    __shared__ float4 sm[2 * F4PB];   // 24 KB: [0,768) pred, [768,1536) true
    const int bid = blockIdx.x, tid = threadIdx.x;
    const int b = bid >> 2, h = bid & 3;
    const size_t base = (size_t)b * (FB / 4) + (size_t)h * F4PB;

    // Coalesced stage: 6 dwordx4 loads in flight, then LDS writes.
    float4 rp0 = pred4[base + 0 * BLK + tid];
    float4 rp1 = pred4[base + 1 * BLK + tid];
    float4 rp2 = pred4[base + 2 * BLK + tid];
    float4 rt0 = tru4 [base + 0 * BLK + tid];
    float4 rt1 = tru4 [base + 1 * BLK + tid];
    float4 rt2 = tru4 [base + 2 * BLK + tid];
    sm[0 * BLK + tid] = rp0;
    sm[1 * BLK + tid] = rp1;
    sm[2 * BLK + tid] = rp2;
    sm[F4PB + 0 * BLK + tid] = rt0;
    sm[F4PB + 1 * BLK + tid] = rt1;
    sm[F4PB + 2 * BLK + tid] = rt2;
    __syncthreads();

    // Each thread reads its own 4 whole points (48B) per array: 3 ds_read_b128
    // at 48B lane stride (4-way bank conflict, ~1.58x on 6 reads — negligible).
    const float* smp = reinterpret_cast<const float*>(&sm[0]);
    const float* smt = reinterpret_cast<const float*>(&sm[F4PB]);
    const float4* pp = reinterpret_cast<const float4*>(smp + tid * 12);
    const float4* tt = reinterpret_cast<const float4*>(smt + tid * 12);
    float4 p0 = pp[0], p1 = pp[1], p2 = pp[2];
    float4 t0 = tt[0], t1 = tt[1], t2 = tt[2];

    float a[STATS];
    #pragma unroll
    for (int i = 0; i < STATS; ++i) a[i] = 0.0f;

#define ACC(px, py, pz, tx, ty, tz) do {                                        \
        a[0] += (px); a[1] += (py); a[2] += (pz);                               \
        a[3] += (tx); a[4] += (ty); a[5] += (tz);                               \
        a[6] = fmaf((px),(px), fmaf((py),(py), fmaf((pz),(pz), a[6])));         \
        a[7] = fmaf((tx),(tx), fmaf((ty),(ty), fmaf((tz),(tz), a[7])));         \
        a[8]  = fmaf((px),(tx), a[8]);  a[9]  = fmaf((px),(ty), a[9]);          \
        a[10] = fmaf((px),(tz), a[10]); a[11] = fmaf((py),(tx), a[11]);         \
        a[12] = fmaf((py),(ty), a[12]); a[13] = fmaf((py),(tz), a[13]);         \
        a[14] = fmaf((pz),(tx), a[14]); a[15] = fmaf((pz),(ty), a[15]);         \
        a[16] = fmaf((pz),(tz), a[16]);                                         \
    } while (0)

    ACC(p0.x, p0.y, p0.z, t0.x, t0.y, t0.z);
    ACC(p0.w, p1.x, p1.y, t0.w, t1.x, t1.y);
    ACC(p1.z, p1.w, p2.x, t1.z, t1.w, t2.x);
    ACC(p2.y, p2.z, p2.w, t2.y, t2.z, t2.w);
#undef ACC

    // 2-stage butterfly -> every 4-lane group holds group sums.
    #pragma unroll
    for (int i = 0; i < STATS; ++i) {
        a[i] += __shfl_xor(a[i], 1, 64);
        a[i] += __shfl_xor(a[i], 2, 64);
    }

    __syncthreads();                       // staged data consumed; reuse LDS for tail
    float* tl = reinterpret_cast<float*>(sm);  // [STATS][68] (row stride 272B, 16B-aligned)
    const int grp = tid >> 2, sub = tid & 3;
    #pragma unroll
    for (int k = 0; k < 5; ++k) {
        const int s = sub + 4 * k;
        if (s < STATS) tl[s * 68 + grp] = a[s];
    }
    __syncthreads();
    if (tid < STATS) {
        const float4* row = reinterpret_cast<const float4*>(&tl[tid * 68]);
        float4 acc4 = row[0];
        #pragma unroll
        for (int k = 1; k < BLK / 16; ++k) {
            float4 v = row[k];
            acc4.x += v.x; acc4.y += v.y; acc4.z += v.z; acc4.w += v.w;
        }
        ws[(size_t)tid * nblocks + bid] = (acc4.x + acc4.y) + (acc4.z + acc4.w);
    }
}

// Kernel 2: per-batch 3x3 closed-form singular values + RMSD, all f32, mean over B.
// Stat-major ws: each stat read is one coalesced float4 (= the 4 split partials).
__global__ __launch_bounds__(1024) void kabsch_finalize(const float* __restrict__ ws,
                                                        float* __restrict__ out,
                                                        int B, int nblocks) {
    const int tid = threadIdx.x;
    float rmsd = 0.0f;
    if (tid < B) {
        float w[STATS];
        #pragma unroll
        for (int s = 0; s < STATS; ++s) {
            float4 v = *reinterpret_cast<const float4*>(&ws[(size_t)s * nblocks + tid * SPLIT]);
            w[s] = (v.x + v.y) + (v.z + v.w);
        }
        const float invN = 1.0f / (float)N_PTS;
        float sp[3] = {w[0], w[1], w[2]};
        float st[3] = {w[3], w[4], w[5]};
        float A[3][3];
        #pragma unroll
        for (int i = 0; i < 3; ++i)
            #pragma unroll
            for (int j = 0; j < 3; ++j)
                A[i][j] = w[8 + i * 3 + j] - sp[i] * st[j] * invN;
        float Sp = w[6] - (sp[0] * sp[0] + sp[1] * sp[1] + sp[2] * sp[2]) * invN;
        float St = w[7] - (st[0] * st[0] + st[1] * st[1] + st[2] * st[2]) * invN;

        float detA = A[0][0] * (A[1][1] * A[2][2] - A[1][2] * A[2][1])
                   - A[0][1] * (A[1][0] * A[2][2] - A[1][2] * A[2][0])
                   + A[0][2] * (A[1][0] * A[2][1] - A[1][1] * A[2][0]);

        // G = A^T A (symmetric, PSD)
        float G00 = A[0][0]*A[0][0] + A[1][0]*A[1][0] + A[2][0]*A[2][0];
        float G11 = A[0][1]*A[0][1] + A[1][1]*A[1][1] + A[2][1]*A[2][1];
        float G22 = A[0][2]*A[0][2] + A[1][2]*A[1][2] + A[2][2]*A[2][2];
        float G01 = A[0][0]*A[0][1] + A[1][0]*A[1][1] + A[2][0]*A[2][1];
        float G02 = A[0][0]*A[0][2] + A[1][0]*A[1][2] + A[2][0]*A[2][2];
        float G12 = A[0][1]*A[0][2] + A[1][1]*A[1][2] + A[2][1]*A[2][2];

        // Closed-form symmetric 3x3 eigenvalues (descending e1 >= e2 >= e3).
        float q = (G00 + G11 + G22) * (1.0f / 3.0f);
        float p1 = G01 * G01 + G02 * G02 + G12 * G12;
        float b00 = G00 - q, b11 = G11 - q, b22 = G22 - q;
        float p2 = b00 * b00 + b11 * b11 + b22 * b22 + 2.0f * p1;
        float p = sqrtf(p2 * (1.0f / 6.0f));
        float e1, e2, e3;
        if (p > 1e-30f + 1e-6f * fabsf(q)) {
            float ip = 1.0f / p;
            float C00 = b00 * ip, C11 = b11 * ip, C22 = b22 * ip;
            float C01 = G01 * ip, C02 = G02 * ip, C12 = G12 * ip;
            float r = 0.5f * (C00 * (C11 * C22 - C12 * C12)
                            - C01 * (C01 * C22 - C12 * C02)
                            + C02 * (C01 * C12 - C11 * C02));
            r = fminf(1.0f, fmaxf(-1.0f, r));
            float phi = acosf(r) * (1.0f / 3.0f);
            e1 = q + 2.0f * p * __cosf(phi);
            e3 = q + 2.0f * p * __cosf(phi + 2.0943951023931953f);  // + 2*pi/3
            e2 = 3.0f * q - e1 - e3;
        } else {
            e1 = e2 = e3 = q;
        }
        float s1 = sqrtf(fmaxf(e1, 0.0f));
        float s2 = sqrtf(fmaxf(e2, 0.0f));
        float s3 = sqrtf(fmaxf(e3, 0.0f));  // smallest singular value
        float d = (detA < 0.0f) ? -1.0f : 1.0f;
        float tr = s1 + s2 + d * s3;
        float msd = (Sp + St - 2.0f * tr) * invN;
        rmsd = sqrtf(fmaxf(msd, 0.0f));
    }

    rmsd = wave_reduce_sum_f32(rmsd);
    __shared__ float red[16];
    const int lane = tid & 63, wid = tid >> 6;
    if (lane == 0) red[wid] = rmsd;
    __syncthreads();
    if (tid == 0) {
        float tot = 0.0f;
        #pragma unroll
        for (int w = 0; w < 16; ++w) tot += red[w];
        out[0] = tot / (float)B;
    }
}

extern "C" void kernel_launch(void* const* d_in, const int* in_sizes, int n_in,
                              void* d_out, int out_size, void* d_ws, size_t ws_size,
                              hipStream_t stream) {
    const float4* pred4 = (const float4*)d_in[0];
    const float4* tru4  = (const float4*)d_in[1];
    float* out = (float*)d_out;
    float* ws = (float*)d_ws;
    const int B = in_sizes[0] / FB;            // 1024
    const int nblocks = B * SPLIT;             // 4096

    kabsch_reduce<<<dim3(nblocks), dim3(BLK), 0, stream>>>(pred4, tru4, ws, nblocks);
    kabsch_finalize<<<dim3(1), dim3(1024), 0, stream>>>(ws, out, B, nblocks);
}

// Round 9
// 25.399 us; speedup vs baseline: 20.9320x; 1.0810x over previous
//
#include <hip/hip_runtime.h>
#include <math.h>

#define N_PTS 4096
#define FB (N_PTS * 3)            // floats per batch = 12288
#define F4B (FB / 4)              // float4s per batch per array = 3072
#define BLK 256
#define STAGES 4                  // 1024 points per stage
#define F4S (F4B / STAGES)        // 768 float4s per stage per array
#define STATS 17

__device__ inline float wave_reduce_sum_f32(float v) {
    #pragma unroll
    for (int off = 32; off > 0; off >>= 1) v += __shfl_xor(v, off, 64);
    return v;
}

// One block per batch: stream all 4096 points through a 24KB LDS tile in 4
// register-double-buffered stages (coalesced 16B-lane-stride loads, r8's
// proven pattern), block-reduce the 17 sufficient statistics, then thread 0
// solves the closed-form 3x3 SVD and writes this batch's RMSD. No cross-block
// communication (r5/r6: per-block device fences = whole-XCD L2 writebacks).
__global__ __launch_bounds__(BLK) void kabsch_batch(const float4* __restrict__ pred4,
                                                    const float4* __restrict__ tru4,
                                                    float* __restrict__ rmsds) {
    __shared__ float4 sm[2 * F4S];     // 24 KB: [0,768) pred, [768,1536) true
    const int b = blockIdx.x, tid = threadIdx.x;
    const size_t base = (size_t)b * F4B;

    // Preload stage 0 (6 coalesced dwordx4 in flight).
    float4 rp0 = pred4[base + 0 * BLK + tid];
    float4 rp1 = pred4[base + 1 * BLK + tid];
    float4 rp2 = pred4[base + 2 * BLK + tid];
    float4 rt0 = tru4 [base + 0 * BLK + tid];
    float4 rt1 = tru4 [base + 1 * BLK + tid];
    float4 rt2 = tru4 [base + 2 * BLK + tid];

    float a[STATS];
    #pragma unroll
    for (int i = 0; i < STATS; ++i) a[i] = 0.0f;

#define ACC(px, py, pz, tx, ty, tz) do {                                        \
        a[0] += (px); a[1] += (py); a[2] += (pz);                               \
        a[3] += (tx); a[4] += (ty); a[5] += (tz);                               \
        a[6] = fmaf((px),(px), fmaf((py),(py), fmaf((pz),(pz), a[6])));         \
        a[7] = fmaf((tx),(tx), fmaf((ty),(ty), fmaf((tz),(tz), a[7])));         \
        a[8]  = fmaf((px),(tx), a[8]);  a[9]  = fmaf((px),(ty), a[9]);          \
        a[10] = fmaf((px),(tz), a[10]); a[11] = fmaf((py),(tx), a[11]);         \
        a[12] = fmaf((py),(ty), a[12]); a[13] = fmaf((py),(tz), a[13]);         \
        a[14] = fmaf((pz),(tx), a[14]); a[15] = fmaf((pz),(ty), a[15]);         \
        a[16] = fmaf((pz),(tz), a[16]);                                         \
    } while (0)

    #pragma unroll
    for (int s = 0; s < STAGES; ++s) {
        // Commit current stage's registers to LDS.
        sm[0 * BLK + tid] = rp0;
        sm[1 * BLK + tid] = rp1;
        sm[2 * BLK + tid] = rp2;
        sm[F4S + 0 * BLK + tid] = rt0;
        sm[F4S + 1 * BLK + tid] = rt1;
        sm[F4S + 2 * BLK + tid] = rt2;
        // Prefetch next stage; these global loads fly during the consume phase.
        if (s < STAGES - 1) {
            const size_t nb = base + (size_t)(s + 1) * F4S;
            rp0 = pred4[nb + 0 * BLK + tid];
            rp1 = pred4[nb + 1 * BLK + tid];
            rp2 = pred4[nb + 2 * BLK + tid];
            rt0 = tru4 [nb + 0 * BLK + tid];
            rt1 = tru4 [nb + 1 * BLK + tid];
            rt2 = tru4 [nb + 2 * BLK + tid];
        }
        __syncthreads();
        // Consume: each thread its own 4 whole points per array (3 ds_read_b128).
        const float* smp = reinterpret_cast<const float*>(&sm[0]);
        const float* smt = reinterpret_cast<const float*>(&sm[F4S]);
        const float4* pp = reinterpret_cast<const float4*>(smp + tid * 12);
        const float4* tt = reinterpret_cast<const float4*>(smt + tid * 12);
        float4 p0 = pp[0], p1 = pp[1], p2 = pp[2];
        float4 t0 = tt[0], t1 = tt[1], t2 = tt[2];
        ACC(p0.x, p0.y, p0.z, t0.x, t0.y, t0.z);
        ACC(p0.w, p1.x, p1.y, t0.w, t1.x, t1.y);
        ACC(p1.z, p1.w, p2.x, t1.z, t1.w, t2.x);
        ACC(p2.y, p2.z, p2.w, t2.y, t2.z, t2.w);
        __syncthreads();
    }
#undef ACC

    // Block reduction: 2-stage butterfly -> 4-lane-group sums, LDS transpose,
    // threads 0..16 row-sum, then scalar stats -> thread 0.
    #pragma unroll
    for (int i = 0; i < STATS; ++i) {
        a[i] += __shfl_xor(a[i], 1, 64);
        a[i] += __shfl_xor(a[i], 2, 64);
    }
    float* tl = reinterpret_cast<float*>(sm);      // [STATS][68], stride 272B
    const int grp = tid >> 2, sub = tid & 3;
    #pragma unroll
    for (int k = 0; k < 5; ++k) {
        const int s = sub + 4 * k;
        if (s < STATS) tl[s * 68 + grp] = a[s];
    }
    __syncthreads();
    float* fin = tl + STATS * 68;                  // scratch past the transpose area
    if (tid < STATS) {
        const float4* row = reinterpret_cast<const float4*>(&tl[tid * 68]);
        float4 acc4 = row[0];
        #pragma unroll
        for (int k = 1; k < BLK / 16; ++k) {
            float4 v = row[k];
            acc4.x += v.x; acc4.y += v.y; acc4.z += v.z; acc4.w += v.w;
        }
        fin[tid] = (acc4.x + acc4.y) + (acc4.z + acc4.w);
    }
    __syncthreads();
    if (tid == 0) {
        float w[STATS];
        #pragma unroll
        for (int i = 0; i < STATS; ++i) w[i] = fin[i];

        const float invN = 1.0f / (float)N_PTS;
        float sp[3] = {w[0], w[1], w[2]};
        float st[3] = {w[3], w[4], w[5]};
        float A[3][3];
        #pragma unroll
        for (int i = 0; i < 3; ++i)
            #pragma unroll
            for (int j = 0; j < 3; ++j)
                A[i][j] = w[8 + i * 3 + j] - sp[i] * st[j] * invN;
        float Sp = w[6] - (sp[0] * sp[0] + sp[1] * sp[1] + sp[2] * sp[2]) * invN;
        float St = w[7] - (st[0] * st[0] + st[1] * st[1] + st[2] * st[2]) * invN;

        float detA = A[0][0] * (A[1][1] * A[2][2] - A[1][2] * A[2][1])
                   - A[0][1] * (A[1][0] * A[2][2] - A[1][2] * A[2][0])
                   + A[0][2] * (A[1][0] * A[2][1] - A[1][1] * A[2][0]);

        // G = A^T A (symmetric, PSD)
        float G00 = A[0][0]*A[0][0] + A[1][0]*A[1][0] + A[2][0]*A[2][0];
        float G11 = A[0][1]*A[0][1] + A[1][1]*A[1][1] + A[2][1]*A[2][1];
        float G22 = A[0][2]*A[0][2] + A[1][2]*A[1][2] + A[2][2]*A[2][2];
        float G01 = A[0][0]*A[0][1] + A[1][0]*A[1][1] + A[2][0]*A[2][1];
        float G02 = A[0][0]*A[0][2] + A[1][0]*A[1][2] + A[2][0]*A[2][2];
        float G12 = A[0][1]*A[0][2] + A[1][1]*A[1][2] + A[2][1]*A[2][2];

        // Closed-form symmetric 3x3 eigenvalues (descending e1 >= e2 >= e3).
        float q = (G00 + G11 + G22) * (1.0f / 3.0f);
        float p1 = G01 * G01 + G02 * G02 + G12 * G12;
        float b00 = G00 - q, b11 = G11 - q, b22 = G22 - q;
        float p2 = b00 * b00 + b11 * b11 + b22 * b22 + 2.0f * p1;
        float p = sqrtf(p2 * (1.0f / 6.0f));
        float e1, e2, e3;
        if (p > 1e-30f + 1e-6f * fabsf(q)) {
            float ip = 1.0f / p;
            float C00 = b00 * ip, C11 = b11 * ip, C22 = b22 * ip;
            float C01 = G01 * ip, C02 = G02 * ip, C12 = G12 * ip;
            float r = 0.5f * (C00 * (C11 * C22 - C12 * C12)
                            - C01 * (C01 * C22 - C12 * C02)
                            + C02 * (C01 * C12 - C11 * C02));
            r = fminf(1.0f, fmaxf(-1.0f, r));
            float phi = acosf(r) * (1.0f / 3.0f);
            e1 = q + 2.0f * p * __cosf(phi);
            e3 = q + 2.0f * p * __cosf(phi + 2.0943951023931953f);  // + 2*pi/3
            e2 = 3.0f * q - e1 - e3;
        } else {
            e1 = e2 = e3 = q;
        }
        float s1 = sqrtf(fmaxf(e1, 0.0f));
        float s2 = sqrtf(fmaxf(e2, 0.0f));
        float s3 = sqrtf(fmaxf(e3, 0.0f));  // smallest singular value
        float d = (detA < 0.0f) ? -1.0f : 1.0f;
        float tr = s1 + s2 + d * s3;
        float msd = (Sp + St - 2.0f * tr) * invN;
        rmsds[b] = sqrtf(fmaxf(msd, 0.0f));
    }
}

// Tiny mean over B per-batch RMSDs: 1 block, 256 threads, one float4 each.
__global__ __launch_bounds__(BLK) void kabsch_mean(const float* __restrict__ rmsds,
                                                   float* __restrict__ out, int B) {
    const int tid = threadIdx.x;
    const float4* r4 = reinterpret_cast<const float4*>(rmsds);
    float4 v = r4[tid];                 // B = 1024 -> 256 float4s
    float s = (v.x + v.y) + (v.z + v.w);
    s = wave_reduce_sum_f32(s);
    __shared__ float red[4];
    if ((tid & 63) == 0) red[tid >> 6] = s;
    __syncthreads();
    if (tid == 0) out[0] = ((red[0] + red[1]) + (red[2] + red[3])) / (float)B;
}

extern "C" void kernel_launch(void* const* d_in, const int* in_sizes, int n_in,
                              void* d_out, int out_size, void* d_ws, size_t ws_size,
                              hipStream_t stream) {
    const float4* pred4 = (const float4*)d_in[0];
    const float4* tru4  = (const float4*)d_in[1];
    float* out = (float*)d_out;
    float* rmsds = (float*)d_ws;
    const int B = in_sizes[0] / FB;     // 1024

    kabsch_batch<<<dim3(B), dim3(BLK), 0, stream>>>(pred4, tru4, rmsds);
    kabsch_mean<<<dim3(1), dim3(BLK), 0, stream>>>(rmsds, out, B);
}

// Round 10
// 23.825 us; speedup vs baseline: 22.3142x; 1.0660x over previous
//
#include <hip/hip_runtime.h>
#include <math.h>

#define N_PTS 4096
#define FB (N_PTS * 3)            // floats per batch = 12288
#define BLK 256
#define STAGES 4                  // 4 points/thread/stage * 4 stages = 16 pts/thread
#define STATS 17

struct __align__(4) f3 { float x, y, z; };

__device__ inline float wave_reduce_sum_f32(float v) {
    #pragma unroll
    for (int off = 32; off > 0; off >>= 1) v += __shfl_xor(v, off, 64);
    return v;
}

// One block per batch, register-only streaming: each thread owns 16 whole
// points loaded as global_load_dwordx3 (12B/lane, lane-stride 12B -> 768B
// contiguous per instruction: coalesced AND point-aligned, so no LDS staging).
// 2-deep pipeline: stage s+1's 8 loads are in flight while stage s's 92 FMAs
// run. r9's LDS round-trip (6 ds_write + 6 ds_read@4-way-conflict + 2 barriers
// per stage ~ 160cyc) cost more than the math it fed (92cyc) — removed.
// No cross-block communication (r5/r6: device fences = whole-XCD L2 flush).
__global__ __launch_bounds__(BLK) void kabsch_batch(const f3* __restrict__ pred,
                                                    const f3* __restrict__ tru,
                                                    float* __restrict__ rmsds) {
    const int b = blockIdx.x, tid = threadIdx.x;
    const f3* Pb = pred + (size_t)b * N_PTS;
    const f3* Tb = tru  + (size_t)b * N_PTS;

    float a[STATS];
    #pragma unroll
    for (int i = 0; i < STATS; ++i) a[i] = 0.0f;

#define ACC(p, t) do {                                                          \
        a[0] += (p).x; a[1] += (p).y; a[2] += (p).z;                            \
        a[3] += (t).x; a[4] += (t).y; a[5] += (t).z;                            \
        a[6] = fmaf((p).x,(p).x, fmaf((p).y,(p).y, fmaf((p).z,(p).z, a[6])));   \
        a[7] = fmaf((t).x,(t).x, fmaf((t).y,(t).y, fmaf((t).z,(t).z, a[7])));   \
        a[8]  = fmaf((p).x,(t).x, a[8]);  a[9]  = fmaf((p).x,(t).y, a[9]);      \
        a[10] = fmaf((p).x,(t).z, a[10]); a[11] = fmaf((p).y,(t).x, a[11]);     \
        a[12] = fmaf((p).y,(t).y, a[12]); a[13] = fmaf((p).y,(t).z, a[13]);     \
        a[14] = fmaf((p).z,(t).x, a[14]); a[15] = fmaf((p).z,(t).y, a[15]);     \
        a[16] = fmaf((p).z,(t).z, a[16]);                                       \
    } while (0)

    // Stage 0 preload (8 dwordx3 in flight).
    f3 pc0 = Pb[0 * BLK + tid], pc1 = Pb[1 * BLK + tid],
       pc2 = Pb[2 * BLK + tid], pc3 = Pb[3 * BLK + tid];
    f3 tc0 = Tb[0 * BLK + tid], tc1 = Tb[1 * BLK + tid],
       tc2 = Tb[2 * BLK + tid], tc3 = Tb[3 * BLK + tid];

    #pragma unroll
    for (int s = 0; s < STAGES; ++s) {
        f3 pn0, pn1, pn2, pn3, tn0, tn1, tn2, tn3;
        if (s < STAGES - 1) {
            const int off = (s + 1) * (STAGES * BLK);   // +1024 points
            pn0 = Pb[off + 0 * BLK + tid]; pn1 = Pb[off + 1 * BLK + tid];
            pn2 = Pb[off + 2 * BLK + tid]; pn3 = Pb[off + 3 * BLK + tid];
            tn0 = Tb[off + 0 * BLK + tid]; tn1 = Tb[off + 1 * BLK + tid];
            tn2 = Tb[off + 2 * BLK + tid]; tn3 = Tb[off + 3 * BLK + tid];
        }
        ACC(pc0, tc0); ACC(pc1, tc1); ACC(pc2, tc2); ACC(pc3, tc3);
        if (s < STAGES - 1) {
            pc0 = pn0; pc1 = pn1; pc2 = pn2; pc3 = pn3;
            tc0 = tn0; tc1 = tn1; tc2 = tn2; tc3 = tn3;
        }
    }
#undef ACC

    // Block reduction: 2-stage butterfly -> 4-lane-group sums, LDS transpose,
    // threads 0..16 row-sum, stats -> LDS, thread 0 eigensolve.
    #pragma unroll
    for (int i = 0; i < STATS; ++i) {
        a[i] += __shfl_xor(a[i], 1, 64);
        a[i] += __shfl_xor(a[i], 2, 64);
    }
    __shared__ float tl[STATS * 68 + 32];          // [STATS][68] stride 272B + scratch
    const int grp = tid >> 2, sub = tid & 3;
    #pragma unroll
    for (int k = 0; k < 5; ++k) {
        const int s = sub + 4 * k;
        if (s < STATS) tl[s * 68 + grp] = a[s];
    }
    __syncthreads();
    float* fin = tl + STATS * 68;
    if (tid < STATS) {
        const float4* row = reinterpret_cast<const float4*>(&tl[tid * 68]);
        float4 acc4 = row[0];
        #pragma unroll
        for (int k = 1; k < BLK / 16; ++k) {
            float4 v = row[k];
            acc4.x += v.x; acc4.y += v.y; acc4.z += v.z; acc4.w += v.w;
        }
        fin[tid] = (acc4.x + acc4.y) + (acc4.z + acc4.w);
    }
    __syncthreads();
    if (tid == 0) {
        float w[STATS];
        #pragma unroll
        for (int i = 0; i < STATS; ++i) w[i] = fin[i];

        const float invN = 1.0f / (float)N_PTS;
        float sp[3] = {w[0], w[1], w[2]};
        float st[3] = {w[3], w[4], w[5]};
        float A[3][3];
        #pragma unroll
        for (int i = 0; i < 3; ++i)
            #pragma unroll
            for (int j = 0; j < 3; ++j)
                A[i][j] = w[8 + i * 3 + j] - sp[i] * st[j] * invN;
        float Sp = w[6] - (sp[0] * sp[0] + sp[1] * sp[1] + sp[2] * sp[2]) * invN;
        float St = w[7] - (st[0] * st[0] + st[1] * st[1] + st[2] * st[2]) * invN;

        float detA = A[0][0] * (A[1][1] * A[2][2] - A[1][2] * A[2][1])
                   - A[0][1] * (A[1][0] * A[2][2] - A[1][2] * A[2][0])
                   + A[0][2] * (A[1][0] * A[2][1] - A[1][1] * A[2][0]);

        // G = A^T A (symmetric, PSD)
        float G00 = A[0][0]*A[0][0] + A[1][0]*A[1][0] + A[2][0]*A[2][0];
        float G11 = A[0][1]*A[0][1] + A[1][1]*A[1][1] + A[2][1]*A[2][1];
        float G22 = A[0][2]*A[0][2] + A[1][2]*A[1][2] + A[2][2]*A[2][2];
        float G01 = A[0][0]*A[0][1] + A[1][0]*A[1][1] + A[2][0]*A[2][1];
        float G02 = A[0][0]*A[0][2] + A[1][0]*A[1][2] + A[2][0]*A[2][2];
        float G12 = A[0][1]*A[0][2] + A[1][1]*A[1][2] + A[2][1]*A[2][2];

        // Closed-form symmetric 3x3 eigenvalues (descending e1 >= e2 >= e3).
        float q = (G00 + G11 + G22) * (1.0f / 3.0f);
        float p1 = G01 * G01 + G02 * G02 + G12 * G12;
        float b00 = G00 - q, b11 = G11 - q, b22 = G22 - q;
        float p2 = b00 * b00 + b11 * b11 + b22 * b22 + 2.0f * p1;
        float p = sqrtf(p2 * (1.0f / 6.0f));
        float e1, e2, e3;
        if (p > 1e-30f + 1e-6f * fabsf(q)) {
            float ip = 1.0f / p;
            float C00 = b00 * ip, C11 = b11 * ip, C22 = b22 * ip;
            float C01 = G01 * ip, C02 = G02 * ip, C12 = G12 * ip;
            float r = 0.5f * (C00 * (C11 * C22 - C12 * C12)
                            - C01 * (C01 * C22 - C12 * C02)
                            + C02 * (C01 * C12 - C11 * C02));
            r = fminf(1.0f, fmaxf(-1.0f, r));
            float phi = acosf(r) * (1.0f / 3.0f);
            e1 = q + 2.0f * p * __cosf(phi);
            e3 = q + 2.0f * p * __cosf(phi + 2.0943951023931953f);  // + 2*pi/3
            e2 = 3.0f * q - e1 - e3;
        } else {
            e1 = e2 = e3 = q;
        }
        float s1 = sqrtf(fmaxf(e1, 0.0f));
        float s2 = sqrtf(fmaxf(e2, 0.0f));
        float s3 = sqrtf(fmaxf(e3, 0.0f));  // smallest singular value
        float d = (detA < 0.0f) ? -1.0f : 1.0f;
        float tr = s1 + s2 + d * s3;
        float msd = (Sp + St - 2.0f * tr) * invN;
        rmsds[b] = sqrtf(fmaxf(msd, 0.0f));
    }
}

// Tiny mean over B per-batch RMSDs: 1 block, 256 threads, one float4 each.
__global__ __launch_bounds__(BLK) void kabsch_mean(const float* __restrict__ rmsds,
                                                   float* __restrict__ out, int B) {
    const int tid = threadIdx.x;
    const float4* r4 = reinterpret_cast<const float4*>(rmsds);
    float4 v = r4[tid];                 // B = 1024 -> 256 float4s
    float s = (v.x + v.y) + (v.z + v.w);
    s = wave_reduce_sum_f32(s);
    __shared__ float red[4];
    if ((tid & 63) == 0) red[tid >> 6] = s;
    __syncthreads();
    if (tid == 0) out[0] = ((red[0] + red[1]) + (red[2] + red[3])) / (float)B;
}

extern "C" void kernel_launch(void* const* d_in, const int* in_sizes, int n_in,
                              void* d_out, int out_size, void* d_ws, size_t ws_size,
                              hipStream_t stream) {
    const f3* pred = (const f3*)d_in[0];
    const f3* tru  = (const f3*)d_in[1];
    float* out = (float*)d_out;
    float* rmsds = (float*)d_ws;
    const int B = in_sizes[0] / FB;     // 1024

    kabsch_batch<<<dim3(B), dim3(BLK), 0, stream>>>(pred, tru, rmsds);
    kabsch_mean<<<dim3(1), dim3(BLK), 0, stream>>>(rmsds, out, B);
}